// Round 10
// baseline (96.257 us; speedup 1.0000x reference)
//
#include <hip/hip_runtime.h>
#include <math.h>

#define NATOMS    128
#define NSEG      7875     // segments: i in [0,124], j in [i+2,126]
#define NSEG_PAD  8192
#define OUT_PER_B 16256    // 128*127 (row-major, diagonal skipped)
#define BLOCK     512
#define TBLOCK    512
#define NCHUNK    2048     // 2016 real chunks (rows padded to x4) + 32 dead
#define CHUNK_BYTES (NCHUNK * 4)
#define WS_NEED   (CHUNK_BYTES + OUT_PER_B * 4)   // 8 KB + 65 KB = 73.2 KB

typedef float v2f __attribute__((ext_vector_type(2)));
__device__ __forceinline__ v2f mk2(float a, float b) { v2f r; r.x = a; r.y = b; return r; }

struct P3 { v2f x, y, z; };
__device__ __forceinline__ P3 psub(P3 a, P3 b) { return {a.x - b.x, a.y - b.y, a.z - b.z}; }
__device__ __forceinline__ P3 pcross(P3 a, P3 b) {
    return {a.y * b.z - a.z * b.y, a.z * b.x - a.x * b.z, a.x * b.y - a.y * b.x};
}
__device__ __forceinline__ v2f pdot(P3 a, P3 b) { return a.x * b.x + a.y * b.y + a.z * b.z; }
__device__ __forceinline__ v2f prsq(v2f q) {
    v2f r; r.x = __builtin_amdgcn_rsqf(q.x); r.y = __builtin_amdgcn_rsqf(q.y); return r;
}
__device__ __forceinline__ v2f pclip1(v2f x) {
    return __builtin_elementwise_min(__builtin_elementwise_max(x, mk2(-1.f, -1.f)),
                                     mk2(1.f, 1.f));
}

// Packed 4-term branchless asin, A&S 4.4.45 (|err| <= 6.8e-5).
__device__ __forceinline__ v2f fast_asin2(v2f x) {
    v2f a = __builtin_elementwise_abs(x);
    v2f p = mk2(-0.0187293f, -0.0187293f);
    p = p * a + mk2( 0.0742610f,  0.0742610f);
    p = p * a + mk2(-0.2121144f, -0.2121144f);
    p = p * a + mk2( 1.5707288f,  1.5707288f);
    v2f om = mk2(1.0f, 1.0f) - a;
    v2f sq; sq.x = __builtin_amdgcn_sqrtf(om.x); sq.y = __builtin_amdgcn_sqrtf(om.y);
    v2f r = mk2(1.57079632679f, 1.57079632679f) - sq * p;
    return __builtin_elementwise_copysign(r, x);
}

__device__ __forceinline__ int seg_row_base(int i) { return 125 * i - (__umul24(i, i - 1) >> 1); }

// (i,j) from linear segment id s (sqrt seed + exact fixup); s must be < NSEG.
__device__ __forceinline__ void seed_ij(int s, int &i, int &j) {
    i = (int)((251.0f - __builtin_amdgcn_sqrtf(63001.0f - 8.0f * (float)s)) * 0.5f);
    i = max(i, 0);
    i += (seg_row_base(i + 1) <= s);
    i += (seg_row_base(i + 1) <= s);
    i -= (seg_row_base(i) > s);
    i -= (seg_row_base(i) > s);
    j = s - seg_row_base(i) + i + 2;
}

__device__ __forceinline__ P3 pack3(const float4 &a, const float4 &b) {
    return { mk2(a.x, b.x), mk2(a.y, b.y), mk2(a.z, b.z) };
}

// =========== table kernel: batch-invariant maps, once per call =============
// gchunk[c]: s0(13b) | j0<<13(7b) | i<<20(7b) | nv<<27(3b). Rows of the
// segment triangle padded to multiples of 4: 2016 real chunks, rest nv=0.
//
// ptab[k]: base0(13b) | base1<<13(13b) | m0<<26(2b) | m1<<28(2b).
// Each pair {base, base+1} is read with ds_read2_b32; mask bits kill invalid
// terms. ROUND-9 BUG FIX: the old encoding clamped the SHARED base
// (clamp(s00,0,NSEG-2)) which mis-anchored edge pairs where only one term is
// valid (e.g. (1,2): s00=-1,v01@0 read swr[1]; (125,127): s00=7874 clamped
// to 7873). Now: base = v0 ? s : (v1 ? s+1 : 0) -- anchored at the VALID
// slot. Both-valid => consecutive ids => base needs no clamp at all. The
// masked partner read may touch uninitialized-but-in-bounds LDS; the select
// discards it.
__global__ __launch_bounds__(TBLOCK) void build_tables(
    unsigned* __restrict__ gchunk,   // u32[2048]
    unsigned* __restrict__ ptab)     // u32[16256]
{
    const int tid = blockIdx.x * TBLOCK + threadIdx.x;

    if (tid < NCHUNK) {
        int c = tid, acc = 0;
        int i = 0, j0 = 2, s0 = 0, nv = 0;
        for (int r = 0; r < 125; ++r) {
            const int len = 125 - r;            // segments in row r
            const int nch = (len + 3) >> 2;
            if (c >= acc && c < acc + nch) {
                const int off = (c - acc) << 2;
                i  = r;
                j0 = r + 2 + off;
                s0 = seg_row_base(r) + off;
                nv = min(4, len - off);
            }
            acc += nch;
        }
        gchunk[tid] = (unsigned)s0 | ((unsigned)j0 << 13)
                    | ((unsigned)i << 20) | ((unsigned)nv << 27);
    } else {
        const int k = tid - NCHUNK;
        if (k < OUT_PER_B) {
            const int r = (int)(((unsigned)k * 132105u) >> 24);   // k/127 exact
            int c = k - r * 127;
            c += (c >= r);
            const int a  = min(r, c);
            const int bb = max(r, c);

            const int am1 = a - 1;
            const int s00 = 125 * am1 - ((am1 * (am1 - 1)) >> 1) + bb - a - 2; // (a-1,b-1)
            const int s10 = s00 + 125 - a;                                     // (a,  b-1)

            const bool v00 = (a >= 1) && (a <= 125) && (bb >= a + 2);
            const bool v01 = (a >= 1) && (a <= 125) && (bb <= 126);
            const bool v10 = (a <= 124) && (bb >= a + 3);
            const bool v11 = (a <= 124) && (bb <= 126) && (bb >= a + 2);

            // Anchor each pair's base at its valid slot (see header comment).
            const int base0 = v00 ? s00 : (v01 ? s00 + 1 : 0);
            const int base1 = v10 ? s10 : (v11 ? s10 + 1 : 0);
            const unsigned m0 = ((v00 || v01) ? 1u : 0u) | ((v00 && v01) ? 2u : 0u);
            const unsigned m1 = ((v10 || v11) ? 1u : 0u) | ((v10 && v11) ? 2u : 0u);

            ptab[k] = (unsigned)base0 | ((unsigned)base1 << 13)
                    | (m0 << 26) | (m1 << 28);
        }
    }
}

// ===================== main kernel: one block per batch =====================
// Phase A: chunk-of-4 sliding window (round-7 measurement: VALU-issue bound,
//   LDS b128 count the next block). Segments (i, j0..j0+3) share p0,p1 and
//   the exact identities n1(s)=m[s+1], n3(s)=-m[s], q3(s)=qm[s]
//   (m[k] = cross(va[k], vb[k])): 7 point loads per 4 segments instead of 16
//   (64 -> ~30 ds_read_b128/thread) and ~8% fewer VALU ops. All state is
//   straight-line within one chunk -- NO loop-carried registers (round-3's
//   spill trap). Two packed chunk-pairs per thread (x-lane/y-lane = chunks).
// Phase D: paired adjacent reads swr[base],swr[base+1] (DS-combiner ->
//   ds_read2_b32: 4 -> 2 LDS ops/output) + cndmask validity via mask bits.
// LDS: sp4 2K + swr 32K = 34 KB. lb(512,2): r7 measured 40 VGPR, no spill;
//   chunk version modeled ~115 peak < 128 cap -- FETCH/WRITE is the tripwire.
__global__ __launch_bounds__(BLOCK, 2) void writhe_main(
    const float*    __restrict__ xyz,     // (B, 128, 3)
    const unsigned* __restrict__ gchunk,  // u32[2048]
    const unsigned* __restrict__ ptab,    // u32[16256]
    float*          __restrict__ out)     // (B, 16256)
{
    __shared__ float4 sp4[NATOMS];
    __shared__ float  swr[NSEG_PAD];

    const int b = blockIdx.x;
    const int t = threadIdx.x;

    if (t < 3 * NATOMS) {
        float v = xyz[(size_t)b * (3 * NATOMS) + t];
        int a = t / 3, c = t - 3 * a;
        ((float*)&sp4[a])[c] = v;
    }
    __syncthreads();

    // ---------- Phase A: 2 packed chunk-pairs x (4 segments each) ----------
    #pragma unroll
    for (int h = 0; h < 2; ++h) {
        const unsigned eA = gchunk[t + h * 1024];
        const unsigned eB = gchunk[t + h * 1024 + 512];

        const int s0A = (int)(eA & 0x1FFFu), j0A = (int)((eA >> 13) & 0x7Fu);
        const int iA  = (int)((eA >> 20) & 0x7Fu), nvA = (int)(eA >> 27);
        const int s0B = (int)(eB & 0x1FFFu), j0B = (int)((eB >> 13) & 0x7Fu);
        const int iB  = (int)((eB >> 20) & 0x7Fu), nvB = (int)(eB >> 27);

        const float4 A0 = sp4[iA], A1 = sp4[iA + 1];
        const float4 B0 = sp4[iB], B1 = sp4[iB + 1];
        const P3 p0 = pack3(A0, B0);
        const P3 p1 = pack3(A1, B1);

        v2f va_x[5], va_y[5], va_z[5];
        v2f vb_x[5], vb_y[5], vb_z[5];
        P3  m[5];
        v2f qm[5];

        #pragma unroll
        for (int k = 0; k < 5; ++k) {
            const float4 Ak = sp4[min(j0A + k, NATOMS - 1)];
            const float4 Bk = sp4[min(j0B + k, NATOMS - 1)];
            const P3 pk = pack3(Ak, Bk);
            const P3 va = psub(pk, p0);
            const P3 vb = psub(pk, p1);
            va_x[k] = va.x; va_y[k] = va.y; va_z[k] = va.z;
            vb_x[k] = vb.x; vb_y[k] = vb.y; vb_z[k] = vb.z;
            m[k]  = pcross(va, vb);
            qm[k] = pdot(m[k], m[k]);
        }

        #pragma unroll
        for (int s = 0; s < 4; ++s) {
            const P3 u0 = {va_x[s],     va_y[s],     va_z[s]};
            const P3 u1 = {va_x[s + 1], va_y[s + 1], va_z[s + 1]};
            const P3 u2 = {vb_x[s],     vb_y[s],     vb_z[s]};
            const P3 u3 = {vb_x[s + 1], vb_y[s + 1], vb_z[s + 1]};

            const P3 n0 = pcross(u0, u1);
            const P3 n2 = pcross(u3, u2);
            const P3 n1 = m[s + 1];              // cross(u1, u3)
            // n3 = cross(u2, u0) = -m[s]; q3 = qm[s]

            const v2f q0 = pdot(n0, n0);
            const v2f q1 = qm[s + 1];
            const v2f q2 = pdot(n2, n2);
            const v2f q3 = qm[s];

            const v2f c0 = pclip1(pdot(n0, n1) * prsq(q0 * q1));
            const v2f c1 = pclip1(pdot(n1, n2) * prsq(q1 * q2));
            const v2f c2 = pclip1((-pdot(n2, m[s])) * prsq(q2 * q3));
            const v2f c3 = pclip1((-pdot(m[s], n0)) * prsq(q3 * q0));

            const v2f sd = pdot(n2, u0);         // = -(reference sd)
            const v2f omega = fast_asin2(c0) + fast_asin2(c1)
                            + fast_asin2(c2) + fast_asin2(c3);

            v2f sgn;
            sgn.x = (sd.x > 0.f) ? -1.f : ((sd.x < 0.f) ? 1.f : 0.f);
            sgn.y = (sd.y > 0.f) ? -1.f : ((sd.y < 0.f) ? 1.f : 0.f);

            const v2f w = omega * sgn * mk2(0.15915494309189535f, 0.15915494309189535f);

            if (s < nvA) swr[s0A + s] = w.x;
            if (s < nvB) swr[s0B + s] = w.y;
        }
    }
    __syncthreads();

    // ---------- Phase D: paired gathers + cndmask validity ----------
    float* ob = out + (size_t)b * OUT_PER_B;
    for (int k = t; k < OUT_PER_B; k += BLOCK) {
        const unsigned e = ptab[k];
        const int s0 = (int)(e & 0x1FFFu);
        const int s1 = (int)((e >> 13) & 0x1FFFu);
        const unsigned vm = e >> 26;             // b0:a0  b1:a1  b2:c0  b3:c1

        const float* b0 = &swr[s0];
        const float* b1 = &swr[s1];
        const float a0 = b0[0], a1 = b0[1];      // one base, +0/+4 -> ds_read2_b32
        const float c0 = b1[0], c1 = b1[1];

        const float sum = ((vm & 1u) ? a0 : 0.f) + ((vm & 2u) ? a1 : 0.f)
                        + ((vm & 4u) ? c0 : 0.f) + ((vm & 8u) ? c1 : 0.f);

        __builtin_nontemporal_store(sum, ob + k);
    }
}

// ================== fused fallback (round-6, verified) =====================
__device__ __forceinline__ v2f seg_writhe_pair(unsigned pa, unsigned pb,
                                               const float4* sp4) {
    int jA = (int)(pa & 127u), iA = (int)(pa >> 7);
    int jB = (int)(pb & 127u), iB = (int)(pb >> 7);
    float4 A0 = sp4[iA], A1 = sp4[iA + 1], A2 = sp4[jA], A3 = sp4[jA + 1];
    float4 B0 = sp4[iB], B1 = sp4[iB + 1], B2 = sp4[jB], B3 = sp4[jB + 1];
    P3 p0 = pack3(A0, B0), p1 = pack3(A1, B1), p2 = pack3(A2, B2), p3 = pack3(A3, B3);
    P3 u0 = psub(p2, p0), u1 = psub(p3, p0), u2 = psub(p2, p1), u3 = psub(p3, p1);
    P3 n0 = pcross(u0, u1), n1 = pcross(u1, u3), n2 = pcross(u3, u2), n3 = pcross(u2, u0);
    v2f q0 = pdot(n0, n0), q1 = pdot(n1, n1), q2 = pdot(n2, n2), q3 = pdot(n3, n3);
    v2f c0 = pclip1(pdot(n0, n1) * prsq(q0 * q1));
    v2f c1 = pclip1(pdot(n1, n2) * prsq(q1 * q2));
    v2f c2 = pclip1(pdot(n2, n3) * prsq(q2 * q3));
    v2f c3 = pclip1(pdot(n3, n0) * prsq(q3 * q0));
    v2f sd = pdot(n2, u0);
    v2f omega = fast_asin2(c0) + fast_asin2(c1) + fast_asin2(c2) + fast_asin2(c3);
    v2f sgn;
    sgn.x = (sd.x > 0.f) ? -1.f : ((sd.x < 0.f) ? 1.f : 0.f);
    sgn.y = (sd.y > 0.f) ? -1.f : ((sd.y < 0.f) ? 1.f : 0.f);
    return omega * sgn * mk2(0.15915494309189535f, 0.15915494309189535f);
}

__global__ __launch_bounds__(BLOCK, 2) void writhe_fused(
    const float* __restrict__ xyz, float* __restrict__ out)
{
    __shared__ float4 sp4[NATOMS];
    __shared__ float  swr[NSEG_PAD];
    __shared__ unsigned short sidx[NSEG_PAD];
    const int b = blockIdx.x;
    const int t = threadIdx.x;
    if (t < 3 * NATOMS) {
        float v = xyz[(size_t)b * (3 * NATOMS) + t];
        int a = t / 3, c = t - 3 * a;
        ((float*)&sp4[a])[c] = v;
    }
    {
        int s = t * 16;
        if (s < NSEG) {
            int i, j; seed_ij(s, i, j);
            #pragma unroll
            for (int k = 0; k < 16; ++k) {
                if (s < NSEG) sidx[s] = (unsigned short)((i << 7) | j);
                ++s; ++j;
                if (j > 126) { ++i; j = i + 2; }
            }
        }
        if (t < NSEG_PAD - NSEG) sidx[NSEG + t] = (unsigned short)((124 << 7) | 126);
    }
    __syncthreads();
    #pragma unroll
    for (int g = 0; g < 4; ++g) {
        const int sA = g * 2048 + t;
        v2f w1 = seg_writhe_pair(sidx[sA],        sidx[sA + 512],  sp4);
        v2f w2 = seg_writhe_pair(sidx[sA + 1024], sidx[sA + 1536], sp4);
        swr[sA]        = w1.x;
        swr[sA + 512]  = w1.y;
        swr[sA + 1024] = w2.x;
        swr[sA + 1536] = w2.y;
    }
    __syncthreads();
    float* ob = out + (size_t)b * OUT_PER_B;
    for (int k = t; k < OUT_PER_B; k += BLOCK) {
        const int r = (int)(((unsigned)k * 132105u) >> 24);
        int c = k - r * 127;
        c += (c >= r);
        const int a  = min(r, c);
        const int bb = max(r, c);
        const int am1 = a - 1;
        const int s00 = 125 * am1 - ((am1 * (am1 - 1)) >> 1) + bb - a - 2;
        const int s10 = s00 + 125 - a;
        const bool v00 = (a >= 1) && (a <= 125) && (bb >= a + 2);
        const bool v01 = (a >= 1) && (a <= 125) && (bb <= 126);
        const bool v10 = (a <= 124) && (bb >= a + 3);
        const bool v11 = (a <= 124) && (bb <= 126) && (bb >= a + 2);
        const int c00 = min(max(s00,     0), NSEG - 1);
        const int c01 = min(max(s00 + 1, 0), NSEG - 1);
        const int c10 = min(max(s10,     0), NSEG - 1);
        const int c11 = min(max(s10 + 1, 0), NSEG - 1);
        float sum = (v00 ? swr[c00] : 0.0f) + (v01 ? swr[c01] : 0.0f)
                  + (v10 ? swr[c10] : 0.0f) + (v11 ? swr[c11] : 0.0f);
        __builtin_nontemporal_store(sum, ob + k);
    }
}

extern "C" void kernel_launch(void* const* d_in, const int* in_sizes, int n_in,
                              void* d_out, int out_size, void* d_ws, size_t ws_size,
                              hipStream_t stream) {
    const float* xyz = (const float*)d_in[0];
    float*       out = (float*)d_out;

    int B = in_sizes[0] / (NATOMS * 3);   // 512 for the reference shapes

    if (d_ws != nullptr && ws_size >= (size_t)WS_NEED) {
        unsigned* gchunk = (unsigned*)d_ws;
        unsigned* ptab   = (unsigned*)((char*)d_ws + CHUNK_BYTES);
        const int tgrid = (NCHUNK + OUT_PER_B + TBLOCK - 1) / TBLOCK;   // 36
        build_tables<<<tgrid, TBLOCK, 0, stream>>>(gchunk, ptab);
        writhe_main<<<B, BLOCK, 0, stream>>>(xyz, gchunk, ptab, out);
    } else {
        writhe_fused<<<B, BLOCK, 0, stream>>>(xyz, out);
    }
}